// Round 8
// baseline (84.246 us; speedup 1.0000x reference)
//
#include <hip/hip_runtime.h>
#include <hip/hip_bf16.h>
#include <stdint.h>

#define N 4096
#define D 512
#define TILE 128
#define BK 256           // fp8 bytes (=elems) per staged K-chunk (2 iters)
#define NB (N / TILE)    // 32

typedef float f32x4 __attribute__((ext_vector_type(4)));
typedef int   i32x8 __attribute__((ext_vector_type(8)));
typedef int   i32x4 __attribute__((ext_vector_type(4)));

// ---------------------------------------------------------------------------
// Kernel 1: fp32 -> fp8 e4m3 (OCP) conversion + fp32 row squared-norms.
// (Proven R4; unchanged.)
// ---------------------------------------------------------------------------
__global__ __launch_bounds__(256) void prep_kernel(const float* __restrict__ x,
                                                   unsigned char* __restrict__ xq,
                                                   float* __restrict__ sq) {
    int row  = blockIdx.x * 4 + (threadIdx.x >> 6);
    int lane = threadIdx.x & 63;
    const float* xr = x + (size_t)row * D + lane * 8;
    float4 v0 = *reinterpret_cast<const float4*>(xr);
    float4 v1 = *reinterpret_cast<const float4*>(xr + 4);

    int w0 = __builtin_amdgcn_cvt_pk_fp8_f32(v0.x, v0.y, 0, false);
    w0     = __builtin_amdgcn_cvt_pk_fp8_f32(v0.z, v0.w, w0, true);
    int w1 = __builtin_amdgcn_cvt_pk_fp8_f32(v1.x, v1.y, 0, false);
    w1     = __builtin_amdgcn_cvt_pk_fp8_f32(v1.z, v1.w, w1, true);
    reinterpret_cast<int2*>(xq + (size_t)row * D)[lane] = make_int2(w0, w1);

    float s = v0.x * v0.x + v0.y * v0.y + v0.z * v0.z + v0.w * v0.w +
              v1.x * v1.x + v1.y * v1.y + v1.z * v1.z + v1.w * v1.w;
    #pragma unroll
    for (int off = 32; off > 0; off >>= 1) s += __shfl_down(s, off);
    if (lane == 0) sq[row] = s;
}

// ---------------------------------------------------------------------------
// Kernel 2: lower-triangle Gram via MX-scaled fp8 MFMA (K=128, unit scales)
// + fused distance epilogue. R8 = R7 with the chunk-index fix: after
// STAGE(256), LDS[r][c] holds global chunk 16 + (c ^ (r&15)), so COMPUTE(s)
// must read LDS chunk ((8s+2q) & 15) ^ lr  (R7 omitted the &15 and read past
// the 16-chunk row into the next row -> absmax 77).
//
// Structure: 3 barriers total (vs 8 in R4), only 2 draining outstanding
// glds. Same glds count (128/block), same ds_read count, same MFMA count.
// LDS 64 KB/block -> 2 blocks/CU (unchanged vs R4's launch_bounds(256,2)).
// Bank math for fragment reads: row*256 B == bank 0 for all rows; bank-group
// = ((chunk^lr)&7)*4; lr spans 0..15 -> all 8 groups x 2-way = free (m136).
// ---------------------------------------------------------------------------
__global__ __launch_bounds__(256, 2) void pairdist_kernel(const unsigned char* __restrict__ xq,
                                                          const float* __restrict__ sq,
                                                          float* __restrict__ out) {
    __shared__ __align__(16) unsigned char As[TILE * BK];  // 32 KB
    __shared__ __align__(16) unsigned char Bs[TILE * BK];  // 32 KB

    // Linear block id -> (bi, bj) with bj <= bi (528 lower-triangular pairs)
    int t  = blockIdx.x;
    int bi = (int)((sqrtf(8.0f * (float)t + 1.0f) - 1.0f) * 0.5f);
    while ((bi + 1) * (bi + 2) / 2 <= t) bi++;
    while (bi * (bi + 1) / 2 > t) bi--;
    int bj = t - bi * (bi + 1) / 2;

    int tid  = threadIdx.x;
    int w    = tid >> 6;        // wave 0..3
    int lane = tid & 63;
    int quad = lane >> 4;       // 0..3
    int lr   = lane & 15;       // 0..15
    int wm   = w >> 1;          // wave row (0..1) -> 64 rows
    int wn   = w & 1;           // wave col (0..1) -> 64 cols

    int ibase = bi * TILE + wm * 64;
    int jbase = bj * TILE + wn * 64;

    // Hoisted epilogue loads: issue early, consumed after the K-loop.
    float sqi[4][4], sqj[4];
    #pragma unroll
    for (int mt = 0; mt < 4; mt++)
        #pragma unroll
        for (int tt = 0; tt < 4; tt++)
            sqi[mt][tt] = sq[ibase + mt * 16 + quad * 4 + tt];
    #pragma unroll
    for (int nt = 0; nt < 4; nt++)
        sqj[nt] = sq[jbase + nt * 16 + lr];

    f32x4 acc[4][4];
    #pragma unroll
    for (int mt = 0; mt < 4; mt++)
        #pragma unroll
        for (int nt = 0; nt < 4; nt++)
            acc[mt][nt] = (f32x4)0.0f;

    // Staging addressing: wave w owns rows [w*32, +32) of each 128-row panel.
    // Per glds instr: 4 rows x 256 B. Row within wave = g*4 + (lane>>4);
    // source chunk = (lane&15) ^ (row&15).
    int srow4 = lane >> 4;   // 0..3
    int sch   = lane & 15;   // LDS chunk

    const unsigned char* gaP[8];
    const unsigned char* gbP[8];
    #pragma unroll
    for (int g = 0; g < 8; g++) {
        int rw  = g * 4 + srow4;                 // row within wave's 32
        int src = (sch ^ (rw & 15)) << 4;        // swizzled byte offset
        gaP[g] = xq + (size_t)(bi * TILE + w * 32 + rw) * D + src;
        gbP[g] = xq + (size_t)(bj * TILE + w * 32 + rw) * D + src;
    }
    unsigned char* la = As + w * 32 * BK;        // wave-uniform LDS bases
    unsigned char* lb = Bs + w * 32 * BK;

#define STAGE(k0)                                                             \
    do {                                                                      \
        _Pragma("unroll")                                                     \
        for (int g = 0; g < 8; g++) {                                         \
            __builtin_amdgcn_global_load_lds(                                 \
                (const __attribute__((address_space(1))) void*)(gaP[g] + (k0)), \
                (__attribute__((address_space(3))) void*)(la + g * 4 * BK),   \
                16, 0, 0);                                                    \
            __builtin_amdgcn_global_load_lds(                                 \
                (const __attribute__((address_space(1))) void*)(gbP[g] + (k0)), \
                (__attribute__((address_space(3))) void*)(lb + g * 4 * BK),   \
                16, 0, 0);                                                    \
        }                                                                     \
    } while (0)

#define COMPUTE(s)                                                            \
    do {                                                                      \
        int c0 = ((((8 * (s) + 2 * quad) & 15) ^ lr) << 4);  /* &15: R8 fix */ \
        int c1 = c0 ^ 16;                                                     \
        i32x8 af[4], bfr[4];                                                  \
        _Pragma("unroll")                                                     \
        for (int mt = 0; mt < 4; mt++) {                                      \
            const unsigned char* rb = As + (wm * 64 + mt * 16 + lr) * BK;     \
            i32x4 lo = *reinterpret_cast<const i32x4*>(rb + c0);              \
            i32x4 hi = *reinterpret_cast<const i32x4*>(rb + c1);              \
            af[mt][0] = lo[0]; af[mt][1] = lo[1]; af[mt][2] = lo[2]; af[mt][3] = lo[3]; \
            af[mt][4] = hi[0]; af[mt][5] = hi[1]; af[mt][6] = hi[2]; af[mt][7] = hi[3]; \
        }                                                                     \
        _Pragma("unroll")                                                     \
        for (int nt = 0; nt < 4; nt++) {                                      \
            const unsigned char* rb = Bs + (wn * 64 + nt * 16 + lr) * BK;     \
            i32x4 lo = *reinterpret_cast<const i32x4*>(rb + c0);              \
            i32x4 hi = *reinterpret_cast<const i32x4*>(rb + c1);              \
            bfr[nt][0] = lo[0]; bfr[nt][1] = lo[1]; bfr[nt][2] = lo[2]; bfr[nt][3] = lo[3]; \
            bfr[nt][4] = hi[0]; bfr[nt][5] = hi[1]; bfr[nt][6] = hi[2]; bfr[nt][7] = hi[3]; \
        }                                                                     \
        _Pragma("unroll")                                                     \
        for (int mt = 0; mt < 4; mt++)                                        \
            _Pragma("unroll")                                                 \
            for (int nt = 0; nt < 4; nt++)                                    \
                acc[mt][nt] = __builtin_amdgcn_mfma_scale_f32_16x16x128_f8f6f4( \
                    af[mt], bfr[nt], acc[mt][nt],                             \
                    0, 0, 0, 0x7F7F7F7F, 0, 0x7F7F7F7F);                      \
    } while (0)

    // Peeled 2-stage pipeline: 3 barriers total.
    STAGE(0);
    __syncthreads();      // drain glds(stage0): staging visible
    COMPUTE(0);           // global chunks 0..15 (k in [0,256))
    COMPUTE(1);
    __syncthreads();      // reads of buf done before overwrite
    STAGE(256);
    __syncthreads();      // drain glds(stage1)
    COMPUTE(2);           // global chunks 16..31 (k in [256,512))
    COMPUTE(3);

#undef STAGE
#undef COMPUTE

    // Epilogue (proven R4): D[m][n] at lane: n = lane&15, m = quad*4 + reg.
    if (bi != bj) {
        #pragma unroll
        for (int mt = 0; mt < 4; mt++) {
            #pragma unroll
            for (int tt = 0; tt < 4; tt++) {
                int i = ibase + mt * 16 + quad * 4 + tt;
                unsigned rowoff = (unsigned)(i * (i - 1) / 2);
                #pragma unroll
                for (int nt = 0; nt < 4; nt++) {
                    int j = jbase + nt * 16 + lr;
                    float d2 = sqi[mt][tt] + sqj[nt] - 2.0f * acc[mt][nt][tt];
                    out[rowoff + (unsigned)j] = sqrtf(fmaxf(d2, 0.0f));
                }
            }
        }
    } else {
        #pragma unroll
        for (int mt = 0; mt < 4; mt++) {
            #pragma unroll
            for (int tt = 0; tt < 4; tt++) {
                int i = ibase + mt * 16 + quad * 4 + tt;
                unsigned rowoff = (unsigned)(i * (i - 1) / 2);
                #pragma unroll
                for (int nt = 0; nt < 4; nt++) {
                    int j = jbase + nt * 16 + lr;
                    if (j < i) {
                        float d2 = sqi[mt][tt] + sqj[nt] - 2.0f * acc[mt][nt][tt];
                        out[rowoff + (unsigned)j] = sqrtf(fmaxf(d2, 0.0f));
                    }
                }
            }
        }
    }
}

extern "C" void kernel_launch(void* const* d_in, const int* in_sizes, int n_in,
                              void* d_out, int out_size, void* d_ws, size_t ws_size,
                              hipStream_t stream) {
    const float* x = (const float*)d_in[0];
    float* out = (float*)d_out;

    // Workspace layout: [0, 2MB) fp8 copy of x; then 16KB of fp32 row norms.
    unsigned char* xq = (unsigned char*)d_ws;
    float* sq = (float*)((char*)d_ws + (size_t)N * D);

    prep_kernel<<<N / 4, 256, 0, stream>>>(x, xq, sq);

    int nblocks = NB * (NB + 1) / 2;  // 528 lower-triangular block pairs
    pairdist_kernel<<<nblocks, 256, 0, stream>>>(xq, sq, out);
}

// Round 9
// 80.650 us; speedup vs baseline: 1.0446x; 1.0446x over previous
//
#include <hip/hip_runtime.h>
#include <hip/hip_bf16.h>
#include <stdint.h>

#define N 4096
#define D 512
#define TILE 128
#define BK 128           // fp8 bytes (=elems) per K-chunk
#define NB (N / TILE)    // 32

typedef float f32x4 __attribute__((ext_vector_type(4)));
typedef int   i32x8 __attribute__((ext_vector_type(8)));
typedef int   i32x4 __attribute__((ext_vector_type(4)));

// ---------------------------------------------------------------------------
// Kernel 1: fp32 -> fp8 e4m3 (OCP) conversion + fp32 row squared-norms.
// (Proven R4; unchanged.)
// ---------------------------------------------------------------------------
__global__ __launch_bounds__(256) void prep_kernel(const float* __restrict__ x,
                                                   unsigned char* __restrict__ xq,
                                                   float* __restrict__ sq) {
    int row  = blockIdx.x * 4 + (threadIdx.x >> 6);
    int lane = threadIdx.x & 63;
    const float* xr = x + (size_t)row * D + lane * 8;
    float4 v0 = *reinterpret_cast<const float4*>(xr);
    float4 v1 = *reinterpret_cast<const float4*>(xr + 4);

    int w0 = __builtin_amdgcn_cvt_pk_fp8_f32(v0.x, v0.y, 0, false);
    w0     = __builtin_amdgcn_cvt_pk_fp8_f32(v0.z, v0.w, w0, true);
    int w1 = __builtin_amdgcn_cvt_pk_fp8_f32(v1.x, v1.y, 0, false);
    w1     = __builtin_amdgcn_cvt_pk_fp8_f32(v1.z, v1.w, w1, true);
    reinterpret_cast<int2*>(xq + (size_t)row * D)[lane] = make_int2(w0, w1);

    float s = v0.x * v0.x + v0.y * v0.y + v0.z * v0.z + v0.w * v0.w +
              v1.x * v1.x + v1.y * v1.y + v1.z * v1.z + v1.w * v1.w;
    #pragma unroll
    for (int off = 32; off > 0; off >>= 1) s += __shfl_down(s, off);
    if (lane == 0) sq[row] = s;
}

// ---------------------------------------------------------------------------
// Kernel 2: lower-triangle Gram via MX-scaled fp8 MFMA (K=128, unit scales)
// + fused distance epilogue. R9 = R4's proven K-loop (BK=128, 8 barriers —
// R8's consolidated-drain variant regressed) + diagonal-tile specialization:
//  - block ids 0..495 = strictly-lower tiles (bj < bi), ids 496..527 = the
//    32 diagonal tiles, scheduled LAST so the 3rd scheduling round (16 CUs
//    while 240 idle) consists of cheap blocks.
//  - diagonal blocks: B panel == A panel -> stage only A (half the glds and
//    half the drain); B-fragments read from As; wave (wm=0,wn=1) covers
//    rows 0-63 x cols 64-127 (j > i always) -> skips ds_read/MFMA/epilogue.
// ---------------------------------------------------------------------------
__global__ __launch_bounds__(256, 2) void pairdist_kernel(const unsigned char* __restrict__ xq,
                                                          const float* __restrict__ sq,
                                                          float* __restrict__ out) {
    __shared__ __align__(16) unsigned char As[TILE * BK];  // 16 KB
    __shared__ __align__(16) unsigned char Bs[TILE * BK];  // 16 KB

    // Block id -> (bi, bj): t<496 strict lower (t = bi(bi-1)/2 + bj, bj<bi);
    // t>=496 -> diagonal tile (bi = bj = t-496).
    int t = blockIdx.x;
    int bi, bj;
    bool diag = (t >= 496);
    if (!diag) {
        bi = (int)((1.0f + sqrtf(8.0f * (float)t + 1.0f)) * 0.5f);
        while (bi * (bi - 1) / 2 > t) bi--;
        while ((bi + 1) * bi / 2 <= t) bi++;
        bj = t - bi * (bi - 1) / 2;
    } else {
        bi = bj = t - 496;
    }

    int tid  = threadIdx.x;
    int w    = tid >> 6;        // wave 0..3
    int lane = tid & 63;
    int quad = lane >> 4;       // 0..3
    int lr   = lane & 15;       // 0..15
    int wm   = w >> 1;          // wave row (0..1) -> 64 rows
    int wn   = w & 1;           // wave col (0..1) -> 64 cols

    int ibase = bi * TILE + wm * 64;
    int jbase = bj * TILE + wn * 64;

    // Diagonal-block wave specialization: (0,1) quadrant is all j>i.
    bool skipw = diag && (wm == 0) && (wn == 1);

    f32x4 acc[4][4];
    #pragma unroll
    for (int mt = 0; mt < 4; mt++)
        #pragma unroll
        for (int nt = 0; nt < 4; nt++)
            acc[mt][nt] = (f32x4)0.0f;

    // Staging (proven R4): wave w stages rows [w*32,+32) per panel, 4 glds
    // of 8 rows each; lane l -> row l>>3, LDS chunk l&7, source chunk
    // (l&7)^(row&7) (XOR swizzle so fragment b128 reads spread across all
    // 8 four-bank groups).
    int srow   = lane >> 3;                 // 0..7
    int schunk = lane & 7;                  // 16B chunk
    int sw     = ((schunk ^ srow) << 4);    // swizzled byte offset in row
    const unsigned char* ga = xq + (size_t)(bi * TILE + w * 32 + srow) * D + sw;
    const unsigned char* gb = xq + (size_t)(bj * TILE + w * 32 + srow) * D + sw;
    unsigned char* la = As + w * 32 * BK;   // wave-uniform LDS bases
    unsigned char* lb = Bs + w * 32 * BK;

    // B-fragment source: diagonal blocks reuse the A panel.
    const unsigned char* Bsrc = diag ? As : Bs;

    for (int k0 = 0; k0 < D; k0 += BK) {
        __syncthreads();   // prev iter's ds_reads done before overwrite
        #pragma unroll
        for (int g = 0; g < 4; g++)
            __builtin_amdgcn_global_load_lds(
                (const __attribute__((address_space(1))) void*)(ga + k0 + (size_t)g * 8 * D),
                (__attribute__((address_space(3))) void*)(la + g * 8 * BK), 16, 0, 0);
        if (!diag) {       // wave-uniform branch
            #pragma unroll
            for (int g = 0; g < 4; g++)
                __builtin_amdgcn_global_load_lds(
                    (const __attribute__((address_space(1))) void*)(gb + k0 + (size_t)g * 8 * D),
                    (__attribute__((address_space(3))) void*)(lb + g * 8 * BK), 16, 0, 0);
        }
        __syncthreads();   // drains vmcnt(0): staging visible

        if (!skipw) {      // wave-uniform: diag wave (0,1) skips compute
            // Fragment (16x16x128 f8f6f4): lane holds A[m=lr][k=quad*32+j],
            // 32 B = 2 x b128 at swizzled chunks c0, c0^1.
            int c0 = (((2 * quad) ^ (lr & 7)) << 4);
            int c1 = c0 ^ 16;
            i32x8 af[4], bfr[4];
            #pragma unroll
            for (int mt = 0; mt < 4; mt++) {
                const unsigned char* rb = As + (wm * 64 + mt * 16 + lr) * BK;
                i32x4 lo = *reinterpret_cast<const i32x4*>(rb + c0);
                i32x4 hi = *reinterpret_cast<const i32x4*>(rb + c1);
                af[mt][0] = lo[0]; af[mt][1] = lo[1]; af[mt][2] = lo[2]; af[mt][3] = lo[3];
                af[mt][4] = hi[0]; af[mt][5] = hi[1]; af[mt][6] = hi[2]; af[mt][7] = hi[3];
            }
            #pragma unroll
            for (int nt = 0; nt < 4; nt++) {
                const unsigned char* rb = Bsrc + (wn * 64 + nt * 16 + lr) * BK;
                i32x4 lo = *reinterpret_cast<const i32x4*>(rb + c0);
                i32x4 hi = *reinterpret_cast<const i32x4*>(rb + c1);
                bfr[nt][0] = lo[0]; bfr[nt][1] = lo[1]; bfr[nt][2] = lo[2]; bfr[nt][3] = lo[3];
                bfr[nt][4] = hi[0]; bfr[nt][5] = hi[1]; bfr[nt][6] = hi[2]; bfr[nt][7] = hi[3];
            }

            #pragma unroll
            for (int mt = 0; mt < 4; mt++)
                #pragma unroll
                for (int nt = 0; nt < 4; nt++)
                    acc[mt][nt] = __builtin_amdgcn_mfma_scale_f32_16x16x128_f8f6f4(
                        af[mt], bfr[nt], acc[mt][nt],
                        0, 0,                 // cbsz=0 (A fp8), blgp=0 (B fp8)
                        0, 0x7F7F7F7F,        // A scale: e8m0 127 = x1.0
                        0, 0x7F7F7F7F);       // B scale: x1.0
        }
    }

    if (skipw) return;   // after last barrier: safe to exit

    // Epilogue (proven R4): D[m][n] at lane: n = lane&15, m = quad*4 + reg.
    float sqi[4][4], sqj[4];
    #pragma unroll
    for (int mt = 0; mt < 4; mt++)
        #pragma unroll
        for (int tt = 0; tt < 4; tt++)
            sqi[mt][tt] = sq[ibase + mt * 16 + quad * 4 + tt];
    #pragma unroll
    for (int nt = 0; nt < 4; nt++)
        sqj[nt] = sq[jbase + nt * 16 + lr];

    // Predicate needed only on diagonal-quadrant waves (wm==wn of a diag
    // block); wave (1,0) of diag blocks and all off-diag waves are fully
    // below the diagonal.
    if (!(diag && wm == wn)) {
        #pragma unroll
        for (int mt = 0; mt < 4; mt++) {
            #pragma unroll
            for (int tt = 0; tt < 4; tt++) {
                int i = ibase + mt * 16 + quad * 4 + tt;
                unsigned rowoff = (unsigned)(i * (i - 1) / 2);
                #pragma unroll
                for (int nt = 0; nt < 4; nt++) {
                    int j = jbase + nt * 16 + lr;
                    float d2 = sqi[mt][tt] + sqj[nt] - 2.0f * acc[mt][nt][tt];
                    out[rowoff + (unsigned)j] = sqrtf(fmaxf(d2, 0.0f));
                }
            }
        }
    } else {
        #pragma unroll
        for (int mt = 0; mt < 4; mt++) {
            #pragma unroll
            for (int tt = 0; tt < 4; tt++) {
                int i = ibase + mt * 16 + quad * 4 + tt;
                unsigned rowoff = (unsigned)(i * (i - 1) / 2);
                #pragma unroll
                for (int nt = 0; nt < 4; nt++) {
                    int j = jbase + nt * 16 + lr;
                    if (j < i) {
                        float d2 = sqi[mt][tt] + sqj[nt] - 2.0f * acc[mt][nt][tt];
                        out[rowoff + (unsigned)j] = sqrtf(fmaxf(d2, 0.0f));
                    }
                }
            }
        }
    }
}

extern "C" void kernel_launch(void* const* d_in, const int* in_sizes, int n_in,
                              void* d_out, int out_size, void* d_ws, size_t ws_size,
                              hipStream_t stream) {
    const float* x = (const float*)d_in[0];
    float* out = (float*)d_out;

    // Workspace layout: [0, 2MB) fp8 copy of x; then 16KB of fp32 row norms.
    unsigned char* xq = (unsigned char*)d_ws;
    float* sq = (float*)((char*)d_ws + (size_t)N * D);

    prep_kernel<<<N / 4, 256, 0, stream>>>(x, xq, sq);

    // 496 strict-lower tiles first, 32 cheap diagonal tiles last.
    int nblocks = 496 + 32;  // 528
    pairdist_kernel<<<nblocks, 256, 0, stream>>>(xq, sq, out);
}